// Round 13
// baseline (448.751 us; speedup 1.0000x reference)
//
#include <hip/hip_runtime.h>
#include <hip/hip_bf16.h>
#include <hip/hip_cooperative_groups.h>
#include <stdint.h>

namespace cg = cooperative_groups;

#define NN 50000
#define NE 800000
#define NODE_IN 256
#define EDGE_OUT 64
#define GLOBAL_IN 128
#define NODE_OUT 256
#define HIDDEN 512
#define K1 320          // NODE_IN + EDGE_OUT (u-part folded into per-graph bias G)
#define N_GRAPHS 64
#define MAXDEG 64       // Poisson(16) tail: P(deg>64) ~ 1e-18 per node; writes guarded
#define MT 391          // m-tiles of 128 rows
#define NBLK MT         // coop grid: 1 block per m-tile; 2/CU capacity = 512 >= 391

typedef __attribute__((ext_vector_type(8))) short bf16x8;
typedef __attribute__((ext_vector_type(4))) float f32x4;
typedef __attribute__((ext_vector_type(4))) unsigned short us4;

__device__ __forceinline__ unsigned short f2bf(float x) {
    union { float f; unsigned int u; } c; c.f = x;
    unsigned int u = c.u;
    unsigned int r = (u + 0x7FFFu + ((u >> 16) & 1u)) >> 16;
    return (unsigned short)r;
}

#define GLD_LDS(gp, lp) __builtin_amdgcn_global_load_lds( \
    (const __attribute__((address_space(1))) unsigned int*)(gp), \
    (__attribute__((address_space(3))) unsigned int*)(lp), 16, 0, 0)

// ---------------- shared phase bodies ----------------
#define PREP_W1 (HIDDEN * K1)                 // 163840
#define PREP_W2 (PREP_W1 + NODE_OUT * HIDDEN) // +131072 = 294912
#define PREP_G  (PREP_W2 + N_GRAPHS * HIDDEN) // +32768  = 327680  (cnt zeroed by memset)

__device__ __forceinline__ void prep_body(int idx,
    const float* __restrict__ W1, const float* __restrict__ W2,
    const float* __restrict__ u, const float* __restrict__ b1,
    unsigned short* __restrict__ W1T, unsigned short* __restrict__ W2T,
    float* __restrict__ G)
{
    if (idx < PREP_W1) {
        int n = idx / K1, k = idx - n * K1;
        W1T[idx] = f2bf(W1[(size_t)k * HIDDEN + n]);          // W1T[n][k], k<320
    } else if (idx < PREP_W2) {
        int j = idx - PREP_W1;
        int n = j / HIDDEN, k = j - n * HIDDEN;
        W2T[j] = f2bf(W2[(size_t)k * NODE_OUT + n]);
    } else if (idx < PREP_G) {
        int j = idx - PREP_W2;
        int g = j >> 9, col = j & 511;
        const float* up = u + (size_t)g * GLOBAL_IN;
        float acc = b1[col];
        #pragma unroll 4
        for (int k = 0; k < GLOBAL_IN; ++k)
            acc += up[k] * W1[(size_t)(K1 + k) * HIDDEN + col];
        G[j] = acc;
    }
}

// segmented mean, wave = 1 node. UNIFORM trip count: every __shfl source lane
// is active (round-10/11 bug fix, proven in round 12). Loads predicated i<cc.
__device__ __forceinline__ void seg_body(int node, int tid,
    const float* __restrict__ edge_attr, const int* __restrict__ perm,
    const int* __restrict__ cnt, unsigned short* __restrict__ comb)
{
    int lane = tid & 63;
    int g = lane >> 4, f = (lane & 15) * 4;
    int c = cnt[node];
    int cc = c < MAXDEG ? c : MAXDEG;        // wave-uniform
    const int* pbase = perm + (size_t)node * MAXDEG;
    int eperm = pbase[lane];                 // one coalesced read = whole bucket
    float4 a0 = make_float4(0.f, 0.f, 0.f, 0.f);
    float4 a1 = make_float4(0.f, 0.f, 0.f, 0.f);
    const int nb = (cc + 7) >> 3;            // uniform loop count for all lanes
    for (int kb = 0; kb < nb; ++kb) {
        int i0 = (kb << 3) + g;              // <= 59
        int i1 = i0 + 4;                     // <= 63
        int e0 = __shfl(eperm, i0, 64);      // all lanes active -> defined
        int e1 = __shfl(eperm, i1, 64);
        if (i0 < cc) {
            const float4 v0 = *(const float4*)(edge_attr + (size_t)e0 * EDGE_OUT + f);
            a0.x += v0.x; a0.y += v0.y; a0.z += v0.z; a0.w += v0.w;
        }
        if (i1 < cc) {
            const float4 v1 = *(const float4*)(edge_attr + (size_t)e1 * EDGE_OUT + f);
            a1.x += v1.x; a1.y += v1.y; a1.z += v1.z; a1.w += v1.w;
        }
    }
    float4 acc = make_float4(a0.x + a1.x, a0.y + a1.y, a0.z + a1.z, a0.w + a1.w);
    #pragma unroll
    for (int off = 16; off < 64; off <<= 1) {
        acc.x += __shfl_xor(acc.x, off, 64);
        acc.y += __shfl_xor(acc.y, off, 64);
        acc.z += __shfl_xor(acc.z, off, 64);
        acc.w += __shfl_xor(acc.w, off, 64);
    }
    if (g == 0) {
        float inv = 1.0f / fmaxf((float)c, 1.0f);
        us4 o = { f2bf(acc.x * inv), f2bf(acc.y * inv),
                  f2bf(acc.z * inv), f2bf(acc.w * inv) };
        *(us4*)(comb + (size_t)node * K1 + NODE_IN + f) = o;
    }
}

// one 128x128 GEMM tile, BK=64, XOR-swizzled LDS (round-9/12 verified structure).
// Static __shared__ inside (direct-array pattern proven in rounds 7/9/12).
// EPI=0: bias = G[batch[row]][col], relu -> bf16 out ; EPI=1: bias=b[col] -> f32 out
template<int EPI>
__device__ __forceinline__ void gemm_tile(
    const unsigned short* __restrict__ A, const unsigned short* __restrict__ B,
    const float* __restrict__ bias, const int* __restrict__ batch,
    void* __restrict__ Cv, int m0, int n0, int M, int N, int K)
{
    __shared__ unsigned short lA[128 * 64];
    __shared__ unsigned short lB[128 * 64];
    const int tid = threadIdx.x;
    const int w = tid >> 6, l = tid & 63;
    const int wr = w >> 1, wc = w & 1;

    f32x4 acc[4][4] = {};

    const unsigned short* pAs[4];
    const unsigned short* pBs[4];
    #pragma unroll
    for (int i = 0; i < 4; ++i) {
        int c = tid + i * 256;
        int row = c >> 3;
        int kg = ((c & 7) ^ (row & 7)) * 8;          // inverse-swizzled source granule
        int gr = m0 + row; if (gr >= M) gr = M - 1;  // clamp (stores guarded)
        pAs[i] = A + (size_t)gr * K + kg;
        pBs[i] = B + (size_t)(n0 + row) * K + kg;
    }

    for (int k0 = 0; k0 < K; k0 += 64) {
        #pragma unroll
        for (int i = 0; i < 4; ++i)
            GLD_LDS(pAs[i] + k0, &lA[(size_t)(tid + i * 256) * 8]);
        #pragma unroll
        for (int i = 0; i < 4; ++i)
            GLD_LDS(pBs[i] + k0, &lB[(size_t)(tid + i * 256) * 8]);
        __syncthreads();

        #pragma unroll
        for (int kk = 0; kk < 2; ++kk) {
            bf16x8 af[4], bfr[4];
            #pragma unroll
            for (int m = 0; m < 4; ++m) {
                int ar = wr * 64 + m * 16 + (l & 15);
                int gran = (kk * 4 + (l >> 4)) ^ (ar & 7);
                af[m] = *(const bf16x8*)&lA[ar * 64 + gran * 8];
            }
            #pragma unroll
            for (int n = 0; n < 4; ++n) {
                int br = wc * 64 + n * 16 + (l & 15);
                int gran = (kk * 4 + (l >> 4)) ^ (br & 7);
                bfr[n] = *(const bf16x8*)&lB[br * 64 + gran * 8];
            }
            #pragma unroll
            for (int m = 0; m < 4; ++m)
                #pragma unroll
                for (int n = 0; n < 4; ++n)
                    acc[m][n] = __builtin_amdgcn_mfma_f32_16x16x32_bf16(af[m], bfr[n], acc[m][n], 0, 0, 0);
        }
        __syncthreads();
    }

    const int cbase = n0 + wc * 64 + (l & 15);
    const int rbase = m0 + wr * 64 + ((l >> 4) << 2);
    if (EPI == 0) {
        unsigned short* C = (unsigned short*)Cv;
        #pragma unroll
        for (int m = 0; m < 4; ++m) {
            #pragma unroll
            for (int j = 0; j < 4; ++j) {
                int row = rbase + m * 16 + j;
                if (row < M) {
                    const float* grow = bias + (size_t)batch[row] * HIDDEN;
                    #pragma unroll
                    for (int n = 0; n < 4; ++n) {
                        int c = cbase + n * 16;
                        float v = acc[m][n][j] + grow[c];
                        v = fmaxf(v, 0.0f);
                        C[(size_t)row * N + c] = f2bf(v);
                    }
                }
            }
        }
    } else {
        float* C = (float*)Cv;
        #pragma unroll
        for (int m = 0; m < 4; ++m) {
            #pragma unroll
            for (int j = 0; j < 4; ++j) {
                int row = rbase + m * 16 + j;
                if (row < M) {
                    #pragma unroll
                    for (int n = 0; n < 4; ++n) {
                        int c = cbase + n * 16;
                        C[(size_t)row * N + c] = acc[m][n][j] + bias[c];
                    }
                }
            }
        }
    }
}

// ---------------- cooperative mega-kernel: 5 phases, 3 grid.syncs ----------------
__global__ __launch_bounds__(256, 2)
void mega(const float* __restrict__ x, const int* __restrict__ src,
          const float* __restrict__ edge_attr, const float* __restrict__ u,
          const int* __restrict__ batch, const float* __restrict__ W1,
          const float* __restrict__ b1, const float* __restrict__ W2,
          const float* __restrict__ b2, float* __restrict__ out,
          int* __restrict__ cnt, int* __restrict__ perm,
          unsigned short* __restrict__ comb, unsigned short* __restrict__ W1T,
          unsigned short* __restrict__ W2T, float* __restrict__ G,
          unsigned short* __restrict__ h)
{
    cg::grid_group grid = cg::this_grid();
    const int tid = threadIdx.x;
    const int bid = blockIdx.x;
    const int gs = NBLK * 256;
    const int gid = bid * 256 + tid;

    // phase A: weight prep + G  ||  perm fill (cnt pre-zeroed by memset)  ||  x->comb
    for (int idx = gid; idx < PREP_G; idx += gs)
        prep_body(idx, W1, W2, u, b1, W1T, W2T, G);
    for (int e = gid; e < NE; e += gs) {
        int s = src[e];
        int pos = atomicAdd(&cnt[s], 1);
        if (pos < MAXDEG) perm[(size_t)s * MAXDEG + pos] = e;
    }
    for (int q = gid; q < NN * 64; q += gs) {
        int node = q >> 6, lane = q & 63;
        const float4 v = *(const float4*)(x + (size_t)node * NODE_IN + lane * 4);
        us4 o = { f2bf(v.x), f2bf(v.y), f2bf(v.z), f2bf(v.w) };
        *(us4*)(comb + (size_t)node * K1 + lane * 4) = o;
    }
    grid.sync();

    // phase B: segmented mean -> comb[:,256:320]
    for (int nb = bid; nb < NN / 4; nb += NBLK) {
        int node = nb * 4 + (tid >> 6);
        seg_body(node, tid, edge_attr, perm, cnt, comb);
    }
    grid.sync();

    // phase C: gemm1 — block bid owns row-panel bid (comb fetched once from HBM)
    #pragma unroll 1
    for (int ni = 0; ni < 4; ++ni)
        gemm_tile<0>(comb, W1T, G, batch, h, bid * 128, ni * 128, NN, HIDDEN, K1);
    grid.sync();

    // phase D: gemm2 — same row-panel; h rows produced by THIS block in phase C
    #pragma unroll 1
    for (int ni = 0; ni < 2; ++ni)
        gemm_tile<1>(h, W2T, b2, nullptr, out, bid * 128, ni * 128, NN, NODE_OUT, HIDDEN);
}

// ---------------- fallback pipeline (round-12 proven) if coop launch fails --------
__global__ __launch_bounds__(256)
void k_prep(const float* __restrict__ W1, const float* __restrict__ W2,
            const float* __restrict__ u, const float* __restrict__ b1,
            unsigned short* __restrict__ W1T, unsigned short* __restrict__ W2T,
            float* __restrict__ G)
{
    int idx = blockIdx.x * 256 + threadIdx.x;
    if (idx < PREP_G) prep_body(idx, W1, W2, u, b1, W1T, W2T, G);
}

__global__ __launch_bounds__(256)
void k_fillx(const int* __restrict__ src, int* __restrict__ cnt,
             int* __restrict__ perm, const float* __restrict__ x,
             unsigned short* __restrict__ comb)
{
    const int gs = gridDim.x * 256;
    for (int e = blockIdx.x * 256 + threadIdx.x; e < NE; e += gs) {
        int s = src[e];
        int pos = atomicAdd(&cnt[s], 1);
        if (pos < MAXDEG) perm[(size_t)s * MAXDEG + pos] = e;
    }
    for (int q = blockIdx.x * 256 + threadIdx.x; q < NN * 64; q += gs) {
        int node = q >> 6, lane = q & 63;
        const float4 v = *(const float4*)(x + (size_t)node * NODE_IN + lane * 4);
        us4 o = { f2bf(v.x), f2bf(v.y), f2bf(v.z), f2bf(v.w) };
        *(us4*)(comb + (size_t)node * K1 + lane * 4) = o;
    }
}

__global__ __launch_bounds__(256)
void k_seg(const float* __restrict__ edge_attr, const int* __restrict__ perm,
           const int* __restrict__ cnt, unsigned short* __restrict__ comb)
{
    int node = blockIdx.x * 4 + (threadIdx.x >> 6);
    if (node < NN) seg_body(node, threadIdx.x, edge_attr, perm, cnt, comb);
}

template<int EPI>
__global__ __launch_bounds__(256)
void k_gemm(const unsigned short* __restrict__ A, const unsigned short* __restrict__ B,
            const float* __restrict__ bias, const int* __restrict__ batch,
            void* __restrict__ Cv, int M, int N, int K)
{
    // T1 bijective XCD swizzle (m204), as in round 12
    const int nwg  = gridDim.x * gridDim.y;
    const int orig = blockIdx.x + gridDim.x * blockIdx.y;
    const int q = nwg >> 3, r = nwg & 7;
    const int xcd = orig & 7, sidx = orig >> 3;
    const int wg = (xcd < r ? xcd * (q + 1) : r * (q + 1) + (xcd - r) * q) + sidx;
    const int m0 = (wg / gridDim.x) * 128;
    const int n0 = (wg % gridDim.x) * 128;
    gemm_tile<EPI>(A, B, bias, batch, Cv, m0, n0, M, N, K);
}

extern "C" void kernel_launch(void* const* d_in, const int* in_sizes, int n_in,
                              void* d_out, int out_size, void* d_ws, size_t ws_size,
                              hipStream_t stream)
{
    const float* x         = (const float*)d_in[0];
    const int*   src       = (const int*)d_in[1];     // row 0 = src
    const float* edge_attr = (const float*)d_in[2];
    const float* u         = (const float*)d_in[3];
    const int*   batch     = (const int*)d_in[4];
    const float* W1        = (const float*)d_in[5];
    const float* b1        = (const float*)d_in[6];
    const float* W2        = (const float*)d_in[7];
    const float* b2        = (const float*)d_in[8];
    float* out = (float*)d_out;

    char* ws = (char*)d_ws;
    int*            cnt    = (int*)(ws);                       //    200,000 B
    int*            perm   = (int*)(ws + 200704);              // 12,800,000 B
    unsigned short* comb   = (unsigned short*)(ws + 13000704); // 32,000,000 B  [NN,320]
    unsigned short* W1T    = (unsigned short*)(ws + 45000704); //    327,680 B  [512,320]
    unsigned short* W2T    = (unsigned short*)(ws + 45328384); //    262,144 B  [256,512]
    float*          G      = (float*)(ws + 45590528);          //    131,072 B  [64,512]
    unsigned short* h      = (unsigned short*)(ws + 45721600); // 51,200,000 B  (end ~97 MB)

    hipMemsetAsync(cnt, 0, 200000, stream);

    void* kargs[] = { (void*)&x, (void*)&src, (void*)&edge_attr, (void*)&u,
                      (void*)&batch, (void*)&W1, (void*)&b1, (void*)&W2,
                      (void*)&b2, (void*)&out, (void*)&cnt, (void*)&perm,
                      (void*)&comb, (void*)&W1T, (void*)&W2T, (void*)&G,
                      (void*)&h };
    hipError_t err = hipLaunchCooperativeKernel((const void*)mega, dim3(NBLK),
                                                dim3(256), kargs, 0, stream);
    if (err != hipSuccess) {
        // fallback: round-12 proven split pipeline
        k_prep<<<(PREP_G + 255) / 256, 256, 0, stream>>>(W1, W2, u, b1, W1T, W2T, G);
        k_fillx<<<2048, 256, 0, stream>>>(src, cnt, perm, x, comb);
        k_seg<<<(NN + 3) / 4, 256, 0, stream>>>(edge_attr, perm, cnt, comb);
        k_gemm<0><<<dim3(HIDDEN / 128, (NN + 127) / 128), 256, 0, stream>>>(
            comb, W1T, G, batch, h, NN, HIDDEN, K1);
        k_gemm<1><<<dim3(NODE_OUT / 128, (NN + 127) / 128), 256, 0, stream>>>(
            h, W2T, b2, nullptr, out, NN, NODE_OUT, HIDDEN);
    }
}

// Round 14
// 197.436 us; speedup vs baseline: 2.2729x; 2.2729x over previous
//
#include <hip/hip_runtime.h>
#include <hip/hip_bf16.h>
#include <stdint.h>

#define NN 50000
#define NE 800000
#define NODE_IN 256
#define EDGE_OUT 64
#define GLOBAL_IN 128
#define NODE_OUT 256
#define HIDDEN 512
#define K1 320          // NODE_IN + EDGE_OUT (u-part folded into per-graph bias G)
#define N_GRAPHS 64
#define MAXDEG 64       // Poisson(16) tail: P(deg>64) ~ 1e-18 per node; writes guarded

typedef __attribute__((ext_vector_type(8))) short bf16x8;
typedef __attribute__((ext_vector_type(4))) float f32x4;
typedef __attribute__((ext_vector_type(4))) unsigned short us4;

__device__ __forceinline__ unsigned short f2bf(float x) {
    union { float f; unsigned int u; } c; c.f = x;
    unsigned int u = c.u;
    unsigned int r = (u + 0x7FFFu + ((u >> 16) & 1u)) >> 16;
    return (unsigned short)r;
}

#define GLD_LDS(gp, lp) __builtin_amdgcn_global_load_lds( \
    (const __attribute__((address_space(1))) unsigned int*)(gp), \
    (__attribute__((address_space(3))) unsigned int*)(lp), 16, 0, 0)

// ---------------- setup: weights/G prep + perm fill + x->comb copy (one launch) ----
#define PREP_W1 (HIDDEN * K1)                 // 163840
#define PREP_W2 (PREP_W1 + NODE_OUT * HIDDEN) // +131072 = 294912
#define PREP_G  (PREP_W2 + N_GRAPHS * HIDDEN) // +32768  = 327680  (cnt zeroed by memset)
__global__ __launch_bounds__(256)
void setup(const float* __restrict__ W1, const float* __restrict__ W2,
           const float* __restrict__ u, const float* __restrict__ b1,
           unsigned short* __restrict__ W1T, unsigned short* __restrict__ W2T,
           float* __restrict__ G,
           const int* __restrict__ src, int* __restrict__ cnt,
           int* __restrict__ perm, const float* __restrict__ x,
           unsigned short* __restrict__ comb)
{
    const int gs = gridDim.x * 256;
    const int gid = blockIdx.x * 256 + threadIdx.x;

    for (int idx = gid; idx < PREP_G; idx += gs) {
        if (idx < PREP_W1) {
            int n = idx / K1, k = idx - n * K1;
            W1T[idx] = f2bf(W1[(size_t)k * HIDDEN + n]);          // W1T[n][k], k<320
        } else if (idx < PREP_W2) {
            int j = idx - PREP_W1;
            int n = j / HIDDEN, k = j - n * HIDDEN;
            W2T[j] = f2bf(W2[(size_t)k * NODE_OUT + n]);
        } else {
            int j = idx - PREP_W2;
            int g = j >> 9, col = j & 511;
            const float* up = u + (size_t)g * GLOBAL_IN;
            float acc = b1[col];
            #pragma unroll 4
            for (int k = 0; k < GLOBAL_IN; ++k)
                acc += up[k] * W1[(size_t)(K1 + k) * HIDDEN + col];
            G[j] = acc;
        }
    }
    for (int e = gid; e < NE; e += gs) {
        int s = src[e];
        int pos = atomicAdd(&cnt[s], 1);
        if (pos < MAXDEG) perm[(size_t)s * MAXDEG + pos] = e;
    }
    for (int q = gid; q < NN * 64; q += gs) {
        int node = q >> 6, lane = q & 63;
        const float4 v = *(const float4*)(x + (size_t)node * NODE_IN + lane * 4);
        us4 o = { f2bf(v.x), f2bf(v.y), f2bf(v.z), f2bf(v.w) };
        *(us4*)(comb + (size_t)node * K1 + lane * 4) = o;
    }
}

// ---------------- seg: segmented mean -> comb[:,256:320] (bf16) ----------------
// wave = 1 node; bucket preloaded coalesced; UNIFORM trip count (round-12 fix) so
// every __shfl source lane is active; loads predicated. 4-deep: 16 edges in
// flight per wave-iteration (slots +0,+4,+8,+12).
__global__ __launch_bounds__(256)
void seg(const float* __restrict__ edge_attr, const int* __restrict__ perm,
         const int* __restrict__ cnt, unsigned short* __restrict__ comb)
{
    int node = blockIdx.x * 4 + (threadIdx.x >> 6);
    if (node >= NN) return;                  // NN%4==0: whole waves only
    int lane = threadIdx.x & 63;
    int g = lane >> 4, f = (lane & 15) * 4;
    int c = cnt[node];
    int cc = c < MAXDEG ? c : MAXDEG;        // wave-uniform
    const int* pbase = perm + (size_t)node * MAXDEG;
    int eperm = pbase[lane];                 // one coalesced read = whole bucket
    float4 a0 = make_float4(0.f, 0.f, 0.f, 0.f);
    float4 a1 = make_float4(0.f, 0.f, 0.f, 0.f);
    float4 a2 = make_float4(0.f, 0.f, 0.f, 0.f);
    float4 a3 = make_float4(0.f, 0.f, 0.f, 0.f);
    const int nb = (cc + 15) >> 4;           // uniform loop count for all lanes
    for (int kb = 0; kb < nb; ++kb) {
        int i0 = (kb << 4) + g;              // max 48+3 = 51
        int i1 = i0 + 4;                     // max 55
        int i2 = i0 + 8;                     // max 59
        int i3 = i0 + 12;                    // max 63
        int e0 = __shfl(eperm, i0, 64);      // all lanes active -> defined
        int e1 = __shfl(eperm, i1, 64);
        int e2 = __shfl(eperm, i2, 64);
        int e3 = __shfl(eperm, i3, 64);
        if (i0 < cc) {
            const float4 v = *(const float4*)(edge_attr + (size_t)e0 * EDGE_OUT + f);
            a0.x += v.x; a0.y += v.y; a0.z += v.z; a0.w += v.w;
        }
        if (i1 < cc) {
            const float4 v = *(const float4*)(edge_attr + (size_t)e1 * EDGE_OUT + f);
            a1.x += v.x; a1.y += v.y; a1.z += v.z; a1.w += v.w;
        }
        if (i2 < cc) {
            const float4 v = *(const float4*)(edge_attr + (size_t)e2 * EDGE_OUT + f);
            a2.x += v.x; a2.y += v.y; a2.z += v.z; a2.w += v.w;
        }
        if (i3 < cc) {
            const float4 v = *(const float4*)(edge_attr + (size_t)e3 * EDGE_OUT + f);
            a3.x += v.x; a3.y += v.y; a3.z += v.z; a3.w += v.w;
        }
    }
    float4 acc = make_float4((a0.x + a1.x) + (a2.x + a3.x),
                             (a0.y + a1.y) + (a2.y + a3.y),
                             (a0.z + a1.z) + (a2.z + a3.z),
                             (a0.w + a1.w) + (a2.w + a3.w));
    #pragma unroll
    for (int off = 16; off < 64; off <<= 1) {
        acc.x += __shfl_xor(acc.x, off, 64);
        acc.y += __shfl_xor(acc.y, off, 64);
        acc.z += __shfl_xor(acc.z, off, 64);
        acc.w += __shfl_xor(acc.w, off, 64);
    }
    if (g == 0) {
        float inv = 1.0f / fmaxf((float)c, 1.0f);
        us4 o = { f2bf(acc.x * inv), f2bf(acc.y * inv),
                  f2bf(acc.z * inv), f2bf(acc.w * inv) };
        *(us4*)(comb + (size_t)node * K1 + NODE_IN + f) = o;
    }
}

// ---------------- bf16 GEMM, C[M,N] = A[M,K] * B[N,K]^T, BK=64 + T1 + T2 ------------
// (round-9/12 verified) LDS tile [128 rows][8 granules of 16B]; granule (row,gpos)
// holds k-granule kt = gpos ^ (row&7); staged via inverse-swizzled global source.
// EPI=0: bias = G[batch[row]][col], relu -> bf16 out ; EPI=1: bias=b[col] -> f32 out
template<int EPI>
__global__ __launch_bounds__(256)
void gemm_bt_128(const unsigned short* __restrict__ A,
                 const unsigned short* __restrict__ B,
                 const float* __restrict__ bias,
                 const int* __restrict__ batch,
                 void* __restrict__ Cv,
                 int M, int N, int K)
{
    __shared__ unsigned short lA[128 * 64];
    __shared__ unsigned short lB[128 * 64];
    const int tid = threadIdx.x;
    const int w = tid >> 6, l = tid & 63;

    // ---- T1: bijective XCD swizzle (m204): same-y panels land on one XCD ----
    const int nwg  = gridDim.x * gridDim.y;
    const int orig = blockIdx.x + gridDim.x * blockIdx.y;
    const int q = nwg >> 3, r = nwg & 7;
    const int xcd = orig & 7, sidx = orig >> 3;
    const int wg = (xcd < r ? xcd * (q + 1) : r * (q + 1) + (xcd - r) * q) + sidx;
    const int m0 = (wg / gridDim.x) * 128;
    const int n0 = (wg % gridDim.x) * 128;

    const int wr = w >> 1, wc = w & 1;

    f32x4 acc[4][4] = {};

    const unsigned short* pAs[4];
    const unsigned short* pBs[4];
    #pragma unroll
    for (int i = 0; i < 4; ++i) {
        int c = tid + i * 256;
        int row = c >> 3;
        int kg = ((c & 7) ^ (row & 7)) * 8;          // inverse-swizzled source granule
        int gr = m0 + row; if (gr >= M) gr = M - 1;  // clamp (stores guarded)
        pAs[i] = A + (size_t)gr * K + kg;
        pBs[i] = B + (size_t)(n0 + row) * K + kg;
    }

    for (int k0 = 0; k0 < K; k0 += 64) {
        #pragma unroll
        for (int i = 0; i < 4; ++i)
            GLD_LDS(pAs[i] + k0, &lA[(size_t)(tid + i * 256) * 8]);
        #pragma unroll
        for (int i = 0; i < 4; ++i)
            GLD_LDS(pBs[i] + k0, &lB[(size_t)(tid + i * 256) * 8]);
        __syncthreads();

        #pragma unroll
        for (int kk = 0; kk < 2; ++kk) {
            bf16x8 af[4], bfr[4];
            #pragma unroll
            for (int m = 0; m < 4; ++m) {
                int ar = wr * 64 + m * 16 + (l & 15);
                int gran = (kk * 4 + (l >> 4)) ^ (ar & 7);
                af[m] = *(const bf16x8*)&lA[ar * 64 + gran * 8];
            }
            #pragma unroll
            for (int n = 0; n < 4; ++n) {
                int br = wc * 64 + n * 16 + (l & 15);
                int gran = (kk * 4 + (l >> 4)) ^ (br & 7);
                bfr[n] = *(const bf16x8*)&lB[br * 64 + gran * 8];
            }
            #pragma unroll
            for (int m = 0; m < 4; ++m)
                #pragma unroll
                for (int n = 0; n < 4; ++n)
                    acc[m][n] = __builtin_amdgcn_mfma_f32_16x16x32_bf16(af[m], bfr[n], acc[m][n], 0, 0, 0);
        }
        __syncthreads();
    }

    const int cbase = n0 + wc * 64 + (l & 15);
    const int rbase = m0 + wr * 64 + ((l >> 4) << 2);
    if (EPI == 0) {
        unsigned short* C = (unsigned short*)Cv;
        #pragma unroll
        for (int m = 0; m < 4; ++m) {
            #pragma unroll
            for (int j = 0; j < 4; ++j) {
                int row = rbase + m * 16 + j;
                if (row < M) {
                    const float* grow = bias + (size_t)batch[row] * HIDDEN;
                    #pragma unroll
                    for (int n = 0; n < 4; ++n) {
                        int c = cbase + n * 16;
                        float v = acc[m][n][j] + grow[c];
                        v = fmaxf(v, 0.0f);
                        C[(size_t)row * N + c] = f2bf(v);
                    }
                }
            }
        }
    } else {
        float* C = (float*)Cv;
        #pragma unroll
        for (int m = 0; m < 4; ++m) {
            #pragma unroll
            for (int j = 0; j < 4; ++j) {
                int row = rbase + m * 16 + j;
                if (row < M) {
                    #pragma unroll
                    for (int n = 0; n < 4; ++n) {
                        int c = cbase + n * 16;
                        C[(size_t)row * N + c] = acc[m][n][j] + bias[c];
                    }
                }
            }
        }
    }
}

extern "C" void kernel_launch(void* const* d_in, const int* in_sizes, int n_in,
                              void* d_out, int out_size, void* d_ws, size_t ws_size,
                              hipStream_t stream)
{
    const float* x         = (const float*)d_in[0];
    const int*   src       = (const int*)d_in[1];     // row 0 = src
    const float* edge_attr = (const float*)d_in[2];
    const float* u         = (const float*)d_in[3];
    const int*   batch     = (const int*)d_in[4];
    const float* W1        = (const float*)d_in[5];
    const float* b1        = (const float*)d_in[6];
    const float* W2        = (const float*)d_in[7];
    const float* b2        = (const float*)d_in[8];
    float* out = (float*)d_out;

    char* ws = (char*)d_ws;
    int*            cnt    = (int*)(ws);                       //    200,000 B
    int*            perm   = (int*)(ws + 200704);              // 12,800,000 B
    unsigned short* comb   = (unsigned short*)(ws + 13000704); // 32,000,000 B  [NN,320]
    unsigned short* W1T    = (unsigned short*)(ws + 45000704); //    327,680 B  [512,320]
    unsigned short* W2T    = (unsigned short*)(ws + 45328384); //    262,144 B  [256,512]
    float*          G      = (float*)(ws + 45590528);          //    131,072 B  [64,512]
    unsigned short* h      = (unsigned short*)(ws + 45721600); // 51,200,000 B  (end ~97 MB)

    hipMemsetAsync(cnt, 0, 200000, stream);

    setup<<<2048, 256, 0, stream>>>(W1, W2, u, b1, W1T, W2T, G,
                                    src, cnt, perm, x, comb);

    seg<<<(NN + 3) / 4, 256, 0, stream>>>(edge_attr, perm, cnt, comb);

    gemm_bt_128<0><<<dim3(HIDDEN / 128, (NN + 127) / 128), 256, 0, stream>>>(
        comb, W1T, G, batch, h, NN, HIDDEN, K1);
    gemm_bt_128<1><<<dim3(NODE_OUT / 128, (NN + 127) / 128), 256, 0, stream>>>(
        h, W2T, b2, nullptr, out, NN, NODE_OUT, HIDDEN);
}